// Round 1
// baseline (306.254 us; speedup 1.0000x reference)
//
#include <hip/hip_runtime.h>

#define S_LEN 2048
#define D_HEAD 128
#define N_HEAD 32            // B*H = 2*16
#define QBLK 128
#define KBLK 64
#define NKT (S_LEN / KBLK)   // 32

typedef short short8 __attribute__((ext_vector_type(8)));
typedef float floatx4 __attribute__((ext_vector_type(4)));

__device__ __forceinline__ unsigned short f2bf(float x) {
  unsigned int u = __float_as_uint(x);
  u += 0x7FFFu + ((u >> 16) & 1u);   // RNE
  return (unsigned short)(u >> 16);
}

__global__ __launch_bounds__(256, 2) void attn_fused(
    const float* __restrict__ Q, const float* __restrict__ K,
    const float* __restrict__ V, float* __restrict__ Out,
    float* __restrict__ Sc)
{
  __shared__ unsigned short Kt[KBLK][136];    // [kv][feat], +8 pad, 272B stride
  __shared__ unsigned short Vts[D_HEAD][72];  // [d][kv],   +8 pad, 144B stride
  __shared__ unsigned short Ps[QBLK][72];     // [q][kv]

  // XCD-aware decode: 8 XCDs, 4 heads per XCD, 16 q-tiles contiguous per head
  const int bid  = blockIdx.x;
  const int slot = bid >> 3;
  const int head = (bid & 7) * 4 + (slot >> 4);
  const int q0   = (slot & 15) * QBLK;

  const float* Qh = Q + (size_t)head * S_LEN * D_HEAD;
  const float* Kh = K + (size_t)head * S_LEN * D_HEAD;
  const float* Vh = V + (size_t)head * S_LEN * D_HEAD;
  float* Oh = Out + (size_t)head * S_LEN * D_HEAD;
  float* Sh = Sc  + (size_t)head * S_LEN * S_LEN;

  const int tid  = threadIdx.x;
  const int wid  = tid >> 6;
  const int lane = tid & 63;
  const int c    = lane & 15;   // MFMA col / A row
  const int g    = lane >> 4;   // k-chunk group

  const float scale = 0.088388347648318447f;  // 1/sqrt(128)

  // ---- Q fragments (A operand): row = lane&15, k = 8*(lane>>4)+e ----
  short8 qf[2][4];
#pragma unroll
  for (int mt = 0; mt < 2; ++mt) {
    const float* qrow = Qh + (size_t)(q0 + wid * 32 + mt * 16 + c) * D_HEAD + g * 8;
#pragma unroll
    for (int ks = 0; ks < 4; ++ks) {
      float4 a = *(const float4*)(qrow + ks * 32);
      float4 b = *(const float4*)(qrow + ks * 32 + 4);
      short8 f;
      f[0] = (short)f2bf(a.x); f[1] = (short)f2bf(a.y);
      f[2] = (short)f2bf(a.z); f[3] = (short)f2bf(a.w);
      f[4] = (short)f2bf(b.x); f[5] = (short)f2bf(b.y);
      f[6] = (short)f2bf(b.z); f[7] = (short)f2bf(b.w);
      qf[mt][ks] = f;
    }
  }

  auto stageK = [&](int kt) {
    const float* src = Kh + (size_t)kt * KBLK * D_HEAD;
#pragma unroll
    for (int i = 0; i < 8; ++i) {
      int id = i * 256 + tid;
      int r = id >> 5, c4 = id & 31;
      float4 v = *(const float4*)(src + r * D_HEAD + c4 * 4);
      uint2 w;
      w.x = (unsigned int)f2bf(v.x * scale) | ((unsigned int)f2bf(v.y * scale) << 16);
      w.y = (unsigned int)f2bf(v.z * scale) | ((unsigned int)f2bf(v.w * scale) << 16);
      *(uint2*)&Kt[r][c4 * 4] = w;
    }
  };

  auto stageV = [&](int kt) {   // transpose: Vts[d][kv] = V[kv][d]
    const float* src = Vh + (size_t)kt * KBLK * D_HEAD;
#pragma unroll
    for (int i = 0; i < 4; ++i) {
      int c4 = (tid & 7) | (i << 3);   // d-quad 0..31
      int rp = tid >> 3;               // kv-pair 0..31
      int r = rp * 2;
      const float* p0 = src + (size_t)r * D_HEAD + c4 * 4;
      float4 a = *(const float4*)p0;
      float4 b = *(const float4*)(p0 + D_HEAD);
      *(unsigned int*)&Vts[c4 * 4 + 0][r] = (unsigned int)f2bf(a.x) | ((unsigned int)f2bf(b.x) << 16);
      *(unsigned int*)&Vts[c4 * 4 + 1][r] = (unsigned int)f2bf(a.y) | ((unsigned int)f2bf(b.y) << 16);
      *(unsigned int*)&Vts[c4 * 4 + 2][r] = (unsigned int)f2bf(a.z) | ((unsigned int)f2bf(b.z) << 16);
      *(unsigned int*)&Vts[c4 * 4 + 3][r] = (unsigned int)f2bf(a.w) | ((unsigned int)f2bf(b.w) << 16);
    }
  };

  // ================= PASS 1: row sums of exp(logits) =================
  float esum[2][4] = {};
  for (int kt = 0; kt < NKT; ++kt) {
    stageK(kt);
    __syncthreads();
#pragma unroll
    for (int nt = 0; nt < 4; ++nt) {
      short8 bf[4];
#pragma unroll
      for (int ks = 0; ks < 4; ++ks)
        bf[ks] = *(const short8*)&Kt[nt * 16 + c][ks * 32 + g * 8];
#pragma unroll
      for (int mt = 0; mt < 2; ++mt) {
        floatx4 acc = {0.f, 0.f, 0.f, 0.f};
#pragma unroll
        for (int ks = 0; ks < 4; ++ks)
          acc = __builtin_amdgcn_mfma_f32_16x16x32_bf16(qf[mt][ks], bf[ks], acc, 0, 0, 0);
        esum[mt][0] += __expf(acc[0]);
        esum[mt][1] += __expf(acc[1]);
        esum[mt][2] += __expf(acc[2]);
        esum[mt][3] += __expf(acc[3]);
      }
    }
    __syncthreads();
  }

  // butterfly over the 16 lanes of each group (cols) -> full row sums
  float rinv[2][4];
#pragma unroll
  for (int mt = 0; mt < 2; ++mt)
#pragma unroll
    for (int j = 0; j < 4; ++j) {
      float s = esum[mt][j];
      s += __shfl_xor(s, 1, 64);
      s += __shfl_xor(s, 2, 64);
      s += __shfl_xor(s, 4, 64);
      s += __shfl_xor(s, 8, 64);
      rinv[mt][j] = 1.0f / s;
    }

  // ================= PASS 2: score write + PV =================
  floatx4 oacc[2][8];
#pragma unroll
  for (int mt = 0; mt < 2; ++mt)
#pragma unroll
    for (int dt = 0; dt < 8; ++dt)
      oacc[mt][dt] = (floatx4){0.f, 0.f, 0.f, 0.f};

  for (int kt = 0; kt < NKT; ++kt) {
    stageK(kt);
    stageV(kt);
    __syncthreads();

    // QK^T -> p -> score(global) + Ps(LDS, bf16)
#pragma unroll
    for (int nt = 0; nt < 4; ++nt) {
      short8 bf[4];
#pragma unroll
      for (int ks = 0; ks < 4; ++ks)
        bf[ks] = *(const short8*)&Kt[nt * 16 + c][ks * 32 + g * 8];
#pragma unroll
      for (int mt = 0; mt < 2; ++mt) {
        floatx4 acc = {0.f, 0.f, 0.f, 0.f};
#pragma unroll
        for (int ks = 0; ks < 4; ++ks)
          acc = __builtin_amdgcn_mfma_f32_16x16x32_bf16(qf[mt][ks], bf[ks], acc, 0, 0, 0);
        float* srow = Sh + (size_t)(q0 + wid * 32 + mt * 16 + 4 * g) * S_LEN
                         + (size_t)kt * KBLK + nt * 16 + c;
#pragma unroll
        for (int j = 0; j < 4; ++j) {
          float p = __expf(acc[j]) * rinv[mt][j];
          srow[(size_t)j * S_LEN] = p;
          Ps[wid * 32 + mt * 16 + 4 * g + j][nt * 16 + c] = f2bf(p);
        }
      }
    }

    // PV: out += P @ V   (A = Ps rows of own wave, B = Vts)
#pragma unroll
    for (int ks = 0; ks < 2; ++ks) {
      short8 pa0 = *(const short8*)&Ps[wid * 32 + c][ks * 32 + g * 8];
      short8 pa1 = *(const short8*)&Ps[wid * 32 + 16 + c][ks * 32 + g * 8];
#pragma unroll
      for (int dt = 0; dt < 8; ++dt) {
        short8 vf = *(const short8*)&Vts[dt * 16 + c][ks * 32 + g * 8];
        oacc[0][dt] = __builtin_amdgcn_mfma_f32_16x16x32_bf16(pa0, vf, oacc[0][dt], 0, 0, 0);
        oacc[1][dt] = __builtin_amdgcn_mfma_f32_16x16x32_bf16(pa1, vf, oacc[1][dt], 0, 0, 0);
      }
    }
    __syncthreads();
  }

  // ---- epilogue: out ----
#pragma unroll
  for (int mt = 0; mt < 2; ++mt)
#pragma unroll
    for (int dt = 0; dt < 8; ++dt)
#pragma unroll
      for (int j = 0; j < 4; ++j)
        Oh[(size_t)(q0 + wid * 32 + mt * 16 + 4 * g + j) * D_HEAD + dt * 16 + c] =
            oacc[mt][dt][j];
}

extern "C" void kernel_launch(void* const* d_in, const int* in_sizes, int n_in,
                              void* d_out, int out_size, void* d_ws, size_t ws_size,
                              hipStream_t stream) {
  (void)in_sizes; (void)n_in; (void)d_ws; (void)ws_size; (void)out_size;
  const float* Q = (const float*)d_in[0];
  const float* K = (const float*)d_in[1];
  const float* V = (const float*)d_in[2];
  float* Out = (float*)d_out;
  float* Sc  = Out + (size_t)N_HEAD * S_LEN * D_HEAD;  // out first, then score
  attn_fused<<<N_HEAD * (S_LEN / QBLK), 256, 0, stream>>>(Q, K, V, Out, Sc);
}

// Round 2
// 264.918 us; speedup vs baseline: 1.1560x; 1.1560x over previous
//
#include <hip/hip_runtime.h>
#include <hip/hip_bf16.h>

#define S_LEN 2048
#define D_HEAD 128
#define N_HEAD 32            // B*H = 2*16
#define QBLK 128
#define KBLK 64
#define NKT (S_LEN / KBLK)   // 32
#define TILE_BYTES 16384     // 64*128*2 = 128*64*2
#define WS_NEED (2ull * N_HEAD * S_LEN * D_HEAD * 2ull)  // Khat + Vhat, bf16

typedef short short8 __attribute__((ext_vector_type(8)));
typedef float floatx4 __attribute__((ext_vector_type(4)));

__device__ __forceinline__ unsigned short f2bf(float x) {
  __hip_bfloat16 h = __float2bfloat16(x);   // RNE, HW cvt
  return *reinterpret_cast<unsigned short*>(&h);
}
__device__ __forceinline__ unsigned int pk2(float lo, float hi) {
  return (unsigned int)f2bf(lo) | ((unsigned int)f2bf(hi) << 16);
}

__device__ __forceinline__ void gload16(const void* g, void* l) {
  __builtin_amdgcn_global_load_lds(
      (const __attribute__((address_space(1))) unsigned int*)g,
      (__attribute__((address_space(3))) unsigned int*)l, 16, 0, 0);
}

// ======================= pre-conversion kernel =======================
// Khat: per (head,kt) a 64x128 bf16 tile stored as the LDS image:
//   byte L = row*256 + (colByte ^ ((row&7)<<4)), K scaled by 1/sqrt(D).
// Vhat: per (head,kt) a 128x64 bf16 tile (transposed: [d][kv]):
//   byte L = d*128 + (kvByte ^ ((d&7)<<4)).
__global__ __launch_bounds__(256) void preconv(
    const float* __restrict__ K, const float* __restrict__ V,
    unsigned short* __restrict__ Khat, unsigned short* __restrict__ Vhat)
{
  const float scale = 0.088388347648318447f;  // 1/sqrt(128)
  const int NKTH = N_HEAD * S_LEN * (D_HEAD / 4);  // 2097152
  int t = blockIdx.x * 256 + threadIdx.x;
  if (t < NKTH) {
    int head = t >> 16;            // S_LEN*(D_HEAD/4) = 65536 per head
    int rem  = t & 65535;
    int s = rem >> 5, c4 = rem & 31;
    float4 v = *(const float4*)(K + ((size_t)head * S_LEN + s) * D_HEAD + c4 * 4);
    int kt = s >> 6, row = s & 63;
    int byte = row * 256 + ((c4 * 8) ^ ((row & 7) << 4));
    uint2 w;
    w.x = pk2(v.x * scale, v.y * scale);
    w.y = pk2(v.z * scale, v.w * scale);
    *(uint2*)((char*)Khat + ((size_t)head * NKT + kt) * TILE_BYTES + byte) = w;
  } else {
    int u = t - NKTH;
    if (u < N_HEAD * (S_LEN / 2) * (D_HEAD / 4)) {
      int head = u >> 15;          // (S_LEN/2)*(D_HEAD/4) = 32768 per head
      int rem  = u & 32767;
      int s2 = rem >> 5, c4 = rem & 31;
      const float* p0 = V + ((size_t)head * S_LEN + s2 * 2) * D_HEAD + c4 * 4;
      float4 a = *(const float4*)p0;
      float4 b = *(const float4*)(p0 + D_HEAD);
      int kt = s2 >> 5;
      int kv = (s2 & 31) * 2;
      char* tbase = (char*)Vhat + ((size_t)head * NKT + kt) * TILE_BYTES;
      float av[4] = {a.x, a.y, a.z, a.w};
      float bv[4] = {b.x, b.y, b.z, b.w};
#pragma unroll
      for (int i = 0; i < 4; ++i) {
        int d = c4 * 4 + i;
        int byte = d * 128 + ((kv * 2) ^ ((d & 7) << 4));
        *(unsigned int*)(tbase + byte) = pk2(av[i], bv[i]);
      }
    }
  }
}

// ======================= main fused attention =======================
__global__ __launch_bounds__(256, 2) void attn_main(
    const float* __restrict__ Q, const unsigned short* __restrict__ Khat,
    const unsigned short* __restrict__ Vhat, float* __restrict__ Out,
    float* __restrict__ Sc)
{
  __shared__ unsigned short Kb[2][KBLK * D_HEAD];   // 2 x 16 KB, LDS-image
  __shared__ unsigned short Vb[2][D_HEAD * KBLK];   // 2 x 16 KB, LDS-image
  __shared__ unsigned short Ps[QBLK * KBLK];        // 16 KB, swizzled

  const int bid  = blockIdx.x;
  const int slot = bid >> 3;
  const int head = (bid & 7) * 4 + (slot >> 4);   // XCD-aware
  const int q0   = (slot & 15) * QBLK;

  const float* Qh = Q + (size_t)head * S_LEN * D_HEAD;
  const char* Ktiles = (const char*)Khat + (size_t)head * NKT * TILE_BYTES;
  const char* Vtiles = (const char*)Vhat + (size_t)head * NKT * TILE_BYTES;
  float* Oh = Out + (size_t)head * S_LEN * D_HEAD;
  float* Sh = Sc  + (size_t)head * S_LEN * S_LEN;

  const int tid  = threadIdx.x;
  const int wid  = tid >> 6;
  const int lane = tid & 63;
  const int c    = lane & 15;
  const int g    = lane >> 4;

  auto stage = [&](const char* gtile, unsigned short* ltile) {
    char* l = (char*)ltile + (tid >> 6) * 1024;
    const char* gp = gtile + tid * 16;
#pragma unroll
    for (int i = 0; i < 4; ++i)
      gload16(gp + i * 4096, l + i * 4096);
  };

  // issue first K stage before anything else (overlap with Q load)
  stage(Ktiles, Kb[0]);

  // ---- Q fragments: row = lane&15, k = 8*(lane>>4)+e ----
  short8 qf[2][4];
#pragma unroll
  for (int mt = 0; mt < 2; ++mt) {
    const float* qrow = Qh + (size_t)(q0 + wid * 32 + mt * 16 + c) * D_HEAD + g * 8;
#pragma unroll
    for (int ks = 0; ks < 4; ++ks) {
      float4 a = *(const float4*)(qrow + ks * 32);
      float4 b = *(const float4*)(qrow + ks * 32 + 4);
      unsigned int p0 = pk2(a.x, a.y), p1 = pk2(a.z, a.w);
      unsigned int p2 = pk2(b.x, b.y), p3 = pk2(b.z, b.w);
      short8 f;
      f[0] = (short)(p0 & 0xffff); f[1] = (short)(p0 >> 16);
      f[2] = (short)(p1 & 0xffff); f[3] = (short)(p1 >> 16);
      f[4] = (short)(p2 & 0xffff); f[5] = (short)(p2 >> 16);
      f[6] = (short)(p3 & 0xffff); f[7] = (short)(p3 >> 16);
      qf[mt][ks] = f;
    }
  }

  auto kfrag = [&](const unsigned short* base, int row, int cb) -> short8 {
    return *(const short8*)((const char*)base + row * 256 + (cb ^ ((row & 7) << 4)));
  };
  auto vfrag = [&](const unsigned short* base, int row, int cb) -> short8 {
    return *(const short8*)((const char*)base + row * 128 + (cb ^ ((row & 7) << 4)));
  };

  // ================= PASS 1: row sums of exp =================
  __syncthreads();   // Kb[0] staged (syncthreads drains vmcnt)
  float esum[2][4] = {};
  int cur = 0;
  for (int kt = 0; kt < NKT; ++kt) {
    if (kt + 1 < NKT) stage(Ktiles + (size_t)(kt + 1) * TILE_BYTES, Kb[cur ^ 1]);
#pragma unroll
    for (int nt = 0; nt < 4; ++nt) {
      int r = nt * 16 + c;
      short8 bf[4];
#pragma unroll
      for (int ks = 0; ks < 4; ++ks)
        bf[ks] = kfrag(Kb[cur], r, ks * 64 + g * 16);
#pragma unroll
      for (int mt = 0; mt < 2; ++mt) {
        floatx4 acc = {0.f, 0.f, 0.f, 0.f};
#pragma unroll
        for (int ks = 0; ks < 4; ++ks)
          acc = __builtin_amdgcn_mfma_f32_16x16x32_bf16(qf[mt][ks], bf[ks], acc, 0, 0, 0);
        esum[mt][0] += __expf(acc[0]);
        esum[mt][1] += __expf(acc[1]);
        esum[mt][2] += __expf(acc[2]);
        esum[mt][3] += __expf(acc[3]);
      }
    }
    __syncthreads();
    cur ^= 1;
  }

  float rinv[2][4];
#pragma unroll
  for (int mt = 0; mt < 2; ++mt)
#pragma unroll
    for (int j = 0; j < 4; ++j) {
      float s = esum[mt][j];
      s += __shfl_xor(s, 1, 64);
      s += __shfl_xor(s, 2, 64);
      s += __shfl_xor(s, 4, 64);
      s += __shfl_xor(s, 8, 64);
      rinv[mt][j] = 1.0f / s;
    }

  // ================= PASS 2: score write + PV =================
  floatx4 oacc[2][8];
#pragma unroll
  for (int mt = 0; mt < 2; ++mt)
#pragma unroll
    for (int dt = 0; dt < 8; ++dt)
      oacc[mt][dt] = (floatx4){0.f, 0.f, 0.f, 0.f};

  cur = 0;
  stage(Ktiles, Kb[0]);
  stage(Vtiles, Vb[0]);
  __syncthreads();

  for (int kt = 0; kt < NKT; ++kt) {
    if (kt + 1 < NKT) {
      stage(Ktiles + (size_t)(kt + 1) * TILE_BYTES, Kb[cur ^ 1]);
      stage(Vtiles + (size_t)(kt + 1) * TILE_BYTES, Vb[cur ^ 1]);
    }

    // QK^T -> p -> score(global f32) + Ps(LDS bf16, wave-private rows)
#pragma unroll
    for (int nt = 0; nt < 4; ++nt) {
      int r = nt * 16 + c;
      short8 bf[4];
#pragma unroll
      for (int ks = 0; ks < 4; ++ks)
        bf[ks] = kfrag(Kb[cur], r, ks * 64 + g * 16);
#pragma unroll
      for (int mt = 0; mt < 2; ++mt) {
        floatx4 acc = {0.f, 0.f, 0.f, 0.f};
#pragma unroll
        for (int ks = 0; ks < 4; ++ks)
          acc = __builtin_amdgcn_mfma_f32_16x16x32_bf16(qf[mt][ks], bf[ks], acc, 0, 0, 0);
        float* srow = Sh + (size_t)(q0 + wid * 32 + mt * 16 + 4 * g) * S_LEN
                         + (size_t)kt * KBLK + nt * 16 + c;
#pragma unroll
        for (int j = 0; j < 4; ++j) {
          float p = __expf(acc[j]) * rinv[mt][j];
          srow[(size_t)j * S_LEN] = p;
          int q = wid * 32 + mt * 16 + 4 * g + j;
          int byte = q * 128 + (((nt * 16 + c) * 2) ^ ((q & 7) << 4));
          *(unsigned short*)((char*)Ps + byte) = f2bf(p);
        }
      }
    }

    // PV: oacc += P @ V
#pragma unroll
    for (int ks = 0; ks < 2; ++ks) {
      int r0 = wid * 32 + c;
      int r1 = wid * 32 + 16 + c;
      short8 pa0 = *(const short8*)((char*)Ps + r0 * 128 + ((ks * 64 + g * 16) ^ ((r0 & 7) << 4)));
      short8 pa1 = *(const short8*)((char*)Ps + r1 * 128 + ((ks * 64 + g * 16) ^ ((r1 & 7) << 4)));
#pragma unroll
      for (int dt = 0; dt < 8; ++dt) {
        short8 vf = vfrag(Vb[cur], dt * 16 + c, ks * 64 + g * 16);
        oacc[0][dt] = __builtin_amdgcn_mfma_f32_16x16x32_bf16(pa0, vf, oacc[0][dt], 0, 0, 0);
        oacc[1][dt] = __builtin_amdgcn_mfma_f32_16x16x32_bf16(pa1, vf, oacc[1][dt], 0, 0, 0);
      }
    }
    __syncthreads();
    cur ^= 1;
  }

  // ---- epilogue ----
#pragma unroll
  for (int mt = 0; mt < 2; ++mt)
#pragma unroll
    for (int dt = 0; dt < 8; ++dt)
#pragma unroll
      for (int j = 0; j < 4; ++j)
        Oh[(size_t)(q0 + wid * 32 + mt * 16 + 4 * g + j) * D_HEAD + dt * 16 + c] =
            oacc[mt][dt][j];
}

// ======================= fallback (proven r1 kernel) =======================
__global__ __launch_bounds__(256, 2) void attn_fused(
    const float* __restrict__ Q, const float* __restrict__ K,
    const float* __restrict__ V, float* __restrict__ Out,
    float* __restrict__ Sc)
{
  __shared__ unsigned short Kt[KBLK][136];
  __shared__ unsigned short Vts[D_HEAD][72];
  __shared__ unsigned short Psl[QBLK][72];

  const int bid  = blockIdx.x;
  const int slot = bid >> 3;
  const int head = (bid & 7) * 4 + (slot >> 4);
  const int q0   = (slot & 15) * QBLK;

  const float* Qh = Q + (size_t)head * S_LEN * D_HEAD;
  const float* Kh = K + (size_t)head * S_LEN * D_HEAD;
  const float* Vh = V + (size_t)head * S_LEN * D_HEAD;
  float* Oh = Out + (size_t)head * S_LEN * D_HEAD;
  float* Sh = Sc  + (size_t)head * S_LEN * S_LEN;

  const int tid  = threadIdx.x;
  const int wid  = tid >> 6;
  const int lane = tid & 63;
  const int c    = lane & 15;
  const int g    = lane >> 4;
  const float scale = 0.088388347648318447f;

  short8 qf[2][4];
#pragma unroll
  for (int mt = 0; mt < 2; ++mt) {
    const float* qrow = Qh + (size_t)(q0 + wid * 32 + mt * 16 + c) * D_HEAD + g * 8;
#pragma unroll
    for (int ks = 0; ks < 4; ++ks) {
      float4 a = *(const float4*)(qrow + ks * 32);
      float4 b = *(const float4*)(qrow + ks * 32 + 4);
      short8 f;
      f[0] = (short)f2bf(a.x); f[1] = (short)f2bf(a.y);
      f[2] = (short)f2bf(a.z); f[3] = (short)f2bf(a.w);
      f[4] = (short)f2bf(b.x); f[5] = (short)f2bf(b.y);
      f[6] = (short)f2bf(b.z); f[7] = (short)f2bf(b.w);
      qf[mt][ks] = f;
    }
  }

  auto stageK = [&](int kt) {
    const float* src = Kh + (size_t)kt * KBLK * D_HEAD;
#pragma unroll
    for (int i = 0; i < 8; ++i) {
      int id = i * 256 + tid;
      int r = id >> 5, c4 = id & 31;
      float4 v = *(const float4*)(src + r * D_HEAD + c4 * 4);
      uint2 w;
      w.x = pk2(v.x * scale, v.y * scale);
      w.y = pk2(v.z * scale, v.w * scale);
      *(uint2*)&Kt[r][c4 * 4] = w;
    }
  };
  auto stageV = [&](int kt) {
    const float* src = Vh + (size_t)kt * KBLK * D_HEAD;
#pragma unroll
    for (int i = 0; i < 4; ++i) {
      int c4 = (tid & 7) | (i << 3);
      int r = (tid >> 3) * 2;
      const float* p0 = src + (size_t)r * D_HEAD + c4 * 4;
      float4 a = *(const float4*)p0;
      float4 b = *(const float4*)(p0 + D_HEAD);
      *(unsigned int*)&Vts[c4 * 4 + 0][r] = pk2(a.x, b.x);
      *(unsigned int*)&Vts[c4 * 4 + 1][r] = pk2(a.y, b.y);
      *(unsigned int*)&Vts[c4 * 4 + 2][r] = pk2(a.z, b.z);
      *(unsigned int*)&Vts[c4 * 4 + 3][r] = pk2(a.w, b.w);
    }
  };

  float esum[2][4] = {};
  for (int kt = 0; kt < NKT; ++kt) {
    stageK(kt);
    __syncthreads();
#pragma unroll
    for (int nt = 0; nt < 4; ++nt) {
      short8 bf[4];
#pragma unroll
      for (int ks = 0; ks < 4; ++ks)
        bf[ks] = *(const short8*)&Kt[nt * 16 + c][ks * 32 + g * 8];
#pragma unroll
      for (int mt = 0; mt < 2; ++mt) {
        floatx4 acc = {0.f, 0.f, 0.f, 0.f};
#pragma unroll
        for (int ks = 0; ks < 4; ++ks)
          acc = __builtin_amdgcn_mfma_f32_16x16x32_bf16(qf[mt][ks], bf[ks], acc, 0, 0, 0);
        esum[mt][0] += __expf(acc[0]);
        esum[mt][1] += __expf(acc[1]);
        esum[mt][2] += __expf(acc[2]);
        esum[mt][3] += __expf(acc[3]);
      }
    }
    __syncthreads();
  }

  float rinv[2][4];
#pragma unroll
  for (int mt = 0; mt < 2; ++mt)
#pragma unroll
    for (int j = 0; j < 4; ++j) {
      float s = esum[mt][j];
      s += __shfl_xor(s, 1, 64);
      s += __shfl_xor(s, 2, 64);
      s += __shfl_xor(s, 4, 64);
      s += __shfl_xor(s, 8, 64);
      rinv[mt][j] = 1.0f / s;
    }

  floatx4 oacc[2][8];
#pragma unroll
  for (int mt = 0; mt < 2; ++mt)
#pragma unroll
    for (int dt = 0; dt < 8; ++dt)
      oacc[mt][dt] = (floatx4){0.f, 0.f, 0.f, 0.f};

  for (int kt = 0; kt < NKT; ++kt) {
    stageK(kt);
    stageV(kt);
    __syncthreads();
#pragma unroll
    for (int nt = 0; nt < 4; ++nt) {
      short8 bf[4];
#pragma unroll
      for (int ks = 0; ks < 4; ++ks)
        bf[ks] = *(const short8*)&Kt[nt * 16 + c][ks * 32 + g * 8];
#pragma unroll
      for (int mt = 0; mt < 2; ++mt) {
        floatx4 acc = {0.f, 0.f, 0.f, 0.f};
#pragma unroll
        for (int ks = 0; ks < 4; ++ks)
          acc = __builtin_amdgcn_mfma_f32_16x16x32_bf16(qf[mt][ks], bf[ks], acc, 0, 0, 0);
        float* srow = Sh + (size_t)(q0 + wid * 32 + mt * 16 + 4 * g) * S_LEN
                         + (size_t)kt * KBLK + nt * 16 + c;
#pragma unroll
        for (int j = 0; j < 4; ++j) {
          float p = __expf(acc[j]) * rinv[mt][j];
          srow[(size_t)j * S_LEN] = p;
          Psl[wid * 32 + mt * 16 + 4 * g + j][nt * 16 + c] = f2bf(p);
        }
      }
    }
#pragma unroll
    for (int ks = 0; ks < 2; ++ks) {
      short8 pa0 = *(const short8*)&Psl[wid * 32 + c][ks * 32 + g * 8];
      short8 pa1 = *(const short8*)&Psl[wid * 32 + 16 + c][ks * 32 + g * 8];
#pragma unroll
      for (int dt = 0; dt < 8; ++dt) {
        short8 vf = *(const short8*)&Vts[dt * 16 + c][ks * 32 + g * 8];
        oacc[0][dt] = __builtin_amdgcn_mfma_f32_16x16x32_bf16(pa0, vf, oacc[0][dt], 0, 0, 0);
        oacc[1][dt] = __builtin_amdgcn_mfma_f32_16x16x32_bf16(pa1, vf, oacc[1][dt], 0, 0, 0);
      }
    }
    __syncthreads();
  }

#pragma unroll
  for (int mt = 0; mt < 2; ++mt)
#pragma unroll
    for (int dt = 0; dt < 8; ++dt)
#pragma unroll
      for (int j = 0; j < 4; ++j)
        Oh[(size_t)(q0 + wid * 32 + mt * 16 + 4 * g + j) * D_HEAD + dt * 16 + c] =
            oacc[mt][dt][j];
}

extern "C" void kernel_launch(void* const* d_in, const int* in_sizes, int n_in,
                              void* d_out, int out_size, void* d_ws, size_t ws_size,
                              hipStream_t stream) {
  (void)in_sizes; (void)n_in; (void)out_size;
  const float* Q = (const float*)d_in[0];
  const float* K = (const float*)d_in[1];
  const float* V = (const float*)d_in[2];
  float* Out = (float*)d_out;
  float* Sc  = Out + (size_t)N_HEAD * S_LEN * D_HEAD;

  if (ws_size >= WS_NEED) {
    unsigned short* Khat = (unsigned short*)d_ws;
    unsigned short* Vhat = Khat + (size_t)N_HEAD * S_LEN * D_HEAD;
    const int total = N_HEAD * S_LEN * (D_HEAD / 4) + N_HEAD * (S_LEN / 2) * (D_HEAD / 4);
    preconv<<<(total + 255) / 256, 256, 0, stream>>>(K, V, Khat, Vhat);
    attn_main<<<N_HEAD * (S_LEN / QBLK), 256, 0, stream>>>(Q, Khat, Vhat, Out, Sc);
  } else {
    attn_fused<<<N_HEAD * (S_LEN / QBLK), 256, 0, stream>>>(Q, K, V, Out, Sc);
  }
}